// Round 6
// baseline (37.199 us; speedup 1.0000x reference)
//
#include <hip/hip_runtime.h>

#define BATCHES  256
#define NVIEWS   20
#define CHANNELS 4096
#define KSEL     7
#define NT       1024        // threads/block; CHANNELS/4 == 1024 float4 chunks
#define NWAVES   (NT / 64)

__global__ __launch_bounds__(NT) void view_select_kernel(
    const float* __restrict__ F0,     // [B, N, C]
    const float* __restrict__ V0,     // [B, N, 3]
    float* __restrict__ out)          // [B*7*C] ++ [B*7*3]
{
    const int b    = blockIdx.x;
    const int t    = threadIdx.x;
    const int wave = t >> 6;
    const int lane = t & 63;

    __shared__ int wh[NWAVES][NVIEWS];   // per-wave histograms (low contention)
    __shared__ int counts[NVIEWS];
    __shared__ int sidx[KSEL];

    if (lane < NVIEWS) wh[wave][lane] = 0;   // own-wave init; program order
                                             // guarantees it precedes the atomics

    // ---- phase 1: load ALL 20 views into registers, argmax, histogram ----
    const float4* Fb4 = (const float4*)(F0 + (size_t)b * NVIEWS * CHANNELS);

    float4 v[NVIEWS];
    #pragma unroll
    for (int n = 0; n < NVIEWS; ++n)
        v[n] = Fb4[(size_t)n * (CHANNELS / 4) + t];

    float4 best = v[0];
    int bi0 = 0, bi1 = 0, bi2 = 0, bi3 = 0;
    #pragma unroll
    for (int n = 1; n < NVIEWS; ++n) {
        if (v[n].x > best.x) { best.x = v[n].x; bi0 = n; }
        if (v[n].y > best.y) { best.y = v[n].y; bi1 = n; }
        if (v[n].z > best.z) { best.z = v[n].z; bi2 = n; }
        if (v[n].w > best.w) { best.w = v[n].w; bi3 = n; }
    }
    atomicAdd(&wh[wave][bi0], 1);
    atomicAdd(&wh[wave][bi1], 1);
    atomicAdd(&wh[wave][bi2], 1);
    atomicAdd(&wh[wave][bi3], 1);
    __syncthreads();

    // combine per-wave histograms
    if (t < NVIEWS) {
        int s = 0;
        #pragma unroll
        for (int w = 0; w < NWAVES; ++w) s += wh[w][t];
        counts[t] = s;
    }
    __syncthreads();

    // ---- phase 2: view selection (thread 0; 20 bins, trivial) ----
    if (t == 0) {
        int u = 0;
        #pragma unroll
        for (int n = 0; n < NVIEWS; ++n) u += (counts[n] > 0) ? 1 : 0;

        if (u >= KSEL) {
            // top-7 by count, ties -> lower view id (== lax.top_k semantics)
            int c[NVIEWS];
            #pragma unroll
            for (int n = 0; n < NVIEWS; ++n) c[n] = counts[n];
            for (int j = 0; j < KSEL; ++j) {
                int bestn = 0, bestc = c[0];
                for (int n = 1; n < NVIEWS; ++n)
                    if (c[n] > bestc) { bestc = c[n]; bestn = n; }
                sidx[j] = bestn;
                c[bestn] = -1;
            }
        } else {
            // sorted unique ids, left-padded with the smallest
            int uniq[NVIEWS]; int m = 0;
            for (int n = 0; n < NVIEWS; ++n)
                if (counts[n] > 0) uniq[m++] = n;
            for (int j = 0; j < KSEL; ++j) {
                int p = j - (KSEL - u);
                if (p < 0) p = 0;
                sidx[j] = uniq[p];
            }
        }
    }
    __syncthreads();

    // ---- phase 3: WRITE-ONLY gather from held registers ----
    float4* out4 = (float4*)out;
    const size_t ob = (size_t)b * KSEL * (CHANNELS / 4);
    #pragma unroll
    for (int j = 0; j < KSEL; ++j) {
        // sidx[j] is block-uniform: force to SGPR so the select chain below
        // is scalar-conditioned register moves (no scratch, no v_cndmask spam)
        int iv = __builtin_amdgcn_readfirstlane(sidx[j]);
        float4 r = v[0];
        #pragma unroll
        for (int n = 1; n < NVIEWS; ++n)
            if (iv == n) r = v[n];     // constant index -> stays in registers
        out4[ob + (size_t)j * (CHANNELS / 4) + t] = r;
    }

    const size_t F_OUT = (size_t)BATCHES * KSEL * CHANNELS;
    if (t < KSEL * 3) {
        int j = t / 3;
        out[F_OUT + (size_t)b * KSEL * 3 + t] =
            V0[(size_t)b * NVIEWS * 3 + (size_t)sidx[j] * 3 + (t % 3)];
    }
}

extern "C" void kernel_launch(void* const* d_in, const int* in_sizes, int n_in,
                              void* d_out, int out_size, void* d_ws, size_t ws_size,
                              hipStream_t stream) {
    const float* F0 = (const float*)d_in[0];
    const float* V0 = (const float*)d_in[1];
    float* out = (float*)d_out;

    view_select_kernel<<<BATCHES, NT, 0, stream>>>(F0, V0, out);
}

// Round 7
// 24.927 us; speedup vs baseline: 1.4923x; 1.4923x over previous
//
#include <hip/hip_runtime.h>

#define BATCHES  256
#define NVIEWS   20
#define CHANNELS 4096
#define KSEL     7
#define NT       1024        // threads/block; CHANNELS/4 == 1024 float4 chunks
#define NWAVES   (NT / 64)

// __launch_bounds__(1024, 4): 4 waves/EU -> 1 block/CU -> 128-VGPR budget.
// Without the 2nd arg the compiler targeted 2 blocks/CU, capped VGPRs at 64,
// and spilled the whole v[20] hold to scratch (R6: VGPR_Count=64, 37 us).
__global__ __launch_bounds__(NT, 4) void view_select_kernel(
    const float* __restrict__ F0,     // [B, N, C]
    const float* __restrict__ V0,     // [B, N, 3]
    float* __restrict__ out)          // [B*7*C] ++ [B*7*3]
{
    const int b    = blockIdx.x;
    const int t    = threadIdx.x;
    const int wave = t >> 6;
    const int lane = t & 63;

    __shared__ int wh[NWAVES][NVIEWS];   // per-wave histograms (low contention)
    __shared__ int counts[NVIEWS];
    __shared__ int sidx[KSEL];

    if (lane < NVIEWS) wh[wave][lane] = 0;   // own-wave init precedes own-wave
                                             // atomics in program order

    // ---- phase 1: load ALL 20 views into registers, argmax, histogram ----
    const float4* Fb4 = (const float4*)(F0 + (size_t)b * NVIEWS * CHANNELS);

    float4 v[NVIEWS];
    #pragma unroll
    for (int n = 0; n < NVIEWS; ++n)
        v[n] = Fb4[(size_t)n * (CHANNELS / 4) + t];

    float4 best = v[0];
    int bi0 = 0, bi1 = 0, bi2 = 0, bi3 = 0;
    #pragma unroll
    for (int n = 1; n < NVIEWS; ++n) {
        if (v[n].x > best.x) { best.x = v[n].x; bi0 = n; }
        if (v[n].y > best.y) { best.y = v[n].y; bi1 = n; }
        if (v[n].z > best.z) { best.z = v[n].z; bi2 = n; }
        if (v[n].w > best.w) { best.w = v[n].w; bi3 = n; }
    }
    atomicAdd(&wh[wave][bi0], 1);
    atomicAdd(&wh[wave][bi1], 1);
    atomicAdd(&wh[wave][bi2], 1);
    atomicAdd(&wh[wave][bi3], 1);
    __syncthreads();

    // combine per-wave histograms
    if (t < NVIEWS) {
        int s = 0;
        #pragma unroll
        for (int w = 0; w < NWAVES; ++w) s += wh[w][t];
        counts[t] = s;
    }
    __syncthreads();

    // ---- phase 2: view selection (thread 0; 20 bins, trivial) ----
    if (t == 0) {
        int u = 0;
        #pragma unroll
        for (int n = 0; n < NVIEWS; ++n) u += (counts[n] > 0) ? 1 : 0;

        if (u >= KSEL) {
            // top-7 by count, ties -> lower view id (== lax.top_k semantics)
            int c[NVIEWS];
            #pragma unroll
            for (int n = 0; n < NVIEWS; ++n) c[n] = counts[n];
            for (int j = 0; j < KSEL; ++j) {
                int bestn = 0, bestc = c[0];
                for (int n = 1; n < NVIEWS; ++n)
                    if (c[n] > bestc) { bestc = c[n]; bestn = n; }
                sidx[j] = bestn;
                c[bestn] = -1;
            }
        } else {
            // sorted unique ids, left-padded with the smallest
            int uniq[NVIEWS]; int m = 0;
            for (int n = 0; n < NVIEWS; ++n)
                if (counts[n] > 0) uniq[m++] = n;
            for (int j = 0; j < KSEL; ++j) {
                int p = j - (KSEL - u);
                if (p < 0) p = 0;
                sidx[j] = uniq[p];
            }
        }
    }
    __syncthreads();

    // ---- phase 3: WRITE-ONLY gather from held registers ----
    // iv is wave-uniform (SGPR): each (j,n) test is a scalar branch, so the
    // untaken 19 bodies are skipped -- no v_cndmask chains, no scratch.
    float4* out4 = (float4*)out;
    const size_t ob = (size_t)b * KSEL * (CHANNELS / 4);
    #pragma unroll
    for (int j = 0; j < KSEL; ++j) {
        int iv = __builtin_amdgcn_readfirstlane(sidx[j]);
        #pragma unroll
        for (int n = 0; n < NVIEWS; ++n) {
            if (iv == n)
                out4[ob + (size_t)j * (CHANNELS / 4) + t] = v[n];
        }
    }

    const size_t F_OUT = (size_t)BATCHES * KSEL * CHANNELS;
    if (t < KSEL * 3) {
        int j = t / 3;
        out[F_OUT + (size_t)b * KSEL * 3 + t] =
            V0[(size_t)b * NVIEWS * 3 + (size_t)sidx[j] * 3 + (t % 3)];
    }
}

extern "C" void kernel_launch(void* const* d_in, const int* in_sizes, int n_in,
                              void* d_out, int out_size, void* d_ws, size_t ws_size,
                              hipStream_t stream) {
    const float* F0 = (const float*)d_in[0];
    const float* V0 = (const float*)d_in[1];
    float* out = (float*)d_out;

    view_select_kernel<<<BATCHES, NT, 0, stream>>>(F0, V0, out);
}